// Round 3
// baseline (1235.464 us; speedup 1.0000x reference)
//
#include <hip/hip_runtime.h>
#include <hip/hip_bf16.h>

using bf16 = __hip_bfloat16;

#define DPB 16   // dst nodes per block in gat_fused
#define EC  64   // edge chunk

// ---------------------------------------------------------------------------
// dual-dtype float load: is_f32 ? f32[i] : bf16[i]
// ---------------------------------------------------------------------------
__device__ __forceinline__ float loadf(const void* p, int i, int is_f32) {
  if (is_f32) return ((const float*)p)[i];
  return __bfloat162float(((const bf16*)p)[i]);
}

// ---------------------------------------------------------------------------
// detect input encodings by content (deterministic):
// flags[0] = floats are f32 (low halfwords parse as huge/NaN bf16)
// flags[1] = edges are int64 (all odd 32-bit words of first half are zero)
// ---------------------------------------------------------------------------
__global__ __launch_bounds__(1024) void detect_kernel(
    const int* __restrict__ ei, const unsigned short* __restrict__ x,
    int* __restrict__ flags) {
  __shared__ int red[1024];
  int t = threadIdx.x;
  int o = 0;
  for (int i = t; i < 2048; i += 1024) o |= ei[2 * i + 1];
  int big = 0;
  for (int i = t; i < 2048; i += 1024) {
    float v = __uint_as_float(((unsigned)x[2 * i]) << 16);
    if (!(fabsf(v) < 1000.f)) big = 1;  // catches huge and NaN
  }
  red[t] = o;
  __syncthreads();
  for (int d = 512; d > 0; d >>= 1) {
    if (t < d) red[t] |= red[t + d];
    __syncthreads();
  }
  int o_all = red[0];
  __syncthreads();
  red[t] = big;
  __syncthreads();
  for (int d = 512; d > 0; d >>= 1) {
    if (t < d) red[t] |= red[t + d];
    __syncthreads();
  }
  if (t == 0) {
    flags[0] = red[0];
    flags[1] = (o_all == 0) ? 1 : 0;
  }
}

// edge accessors honoring int32/int64 layout (ei viewed as int32 words)
__device__ __forceinline__ int edge_src(const int* ei, int E, int e, int i64) {
  return i64 ? ei[2 * e] : ei[e];
}
__device__ __forceinline__ int edge_dst(const int* ei, int E, int e, int i64) {
  return i64 ? ei[2 * E + 2 * e] : ei[E + e];
}

// ---------------------------------------------------------------------------
// prep: vj[h*64+f] = sum_c att_j[h,c] * W[h*64+c, f]   (8x64 fp32)
//       Wr[(h*64+f)*64 + c] = W[(h*64+c)*64 + f]       (512x64 bf16)
// ---------------------------------------------------------------------------
__global__ __launch_bounds__(256) void prep_weights(
    const void* __restrict__ W, const void* __restrict__ att,
    const int* __restrict__ flags, float* __restrict__ vj,
    bf16* __restrict__ Wr) {
  int is_f32 = flags[0];
  int t = blockIdx.x * blockDim.x + threadIdx.x;
  if (t < 32768) {
    int c = t & 63, hf = t >> 6;
    int h = hf >> 6, f = hf & 63;
    Wr[t] = __float2bfloat16(loadf(W, ((h << 6) + c) * 64 + f, is_f32));
  }
  if (t < 512) {
    int hh = t >> 6, ff = t & 63;
    float s = 0.f;
    for (int cc = 0; cc < 64; ++cc)
      s += loadf(att, hh * 128 + 64 + cc, is_f32) *
           loadf(W, ((hh << 6) + cc) * 64 + ff, is_f32);
    vj[t] = s;
  }
}

// ---------------------------------------------------------------------------
// node transform: h = elu(x @ W.T + b)  [N,64] -> bf16, optional a_j = h . v_j
// one wave per node, lane = output channel
// ---------------------------------------------------------------------------
template <int FIN>
__global__ __launch_bounds__(256) void node_transform(
    const void* __restrict__ x, const void* __restrict__ W,
    const void* __restrict__ b, const int* __restrict__ flags,
    const float* __restrict__ vj, bf16* __restrict__ h_out,
    float* __restrict__ aj_out, int N) {
  int is_f32 = flags[0];
  int wave = threadIdx.x >> 6, lane = threadIdx.x & 63;
  int n = blockIdx.x * 4 + wave;
  if (n >= N) return;
  float acc = loadf(b, lane, is_f32);
#pragma unroll
  for (int f = 0; f < FIN; ++f)
    acc += loadf(x, n * FIN + f, is_f32) * loadf(W, lane * FIN + f, is_f32);
  float hv = acc > 0.f ? acc : expm1f(acc);
  h_out[(size_t)n * 64 + lane] = __float2bfloat16(hv);
  if (aj_out) {
#pragma unroll
    for (int hh = 0; hh < 8; ++hh) {
      float p = hv * vj[hh * 64 + lane];
#pragma unroll
      for (int o = 32; o >= 1; o >>= 1) p += __shfl_xor(p, o, 64);
      if (lane == 0) aj_out[(size_t)n * 8 + hh] = p;
    }
  }
}

// ---------------------------------------------------------------------------
// CSR build
// ---------------------------------------------------------------------------
__global__ __launch_bounds__(256) void count_edges(
    const int* __restrict__ ei, int E, const int* __restrict__ flags,
    int* __restrict__ cnt_dst, int* __restrict__ cnt_src) {
  int i64 = flags[1];
  int e = blockIdx.x * blockDim.x + threadIdx.x;
  if (e < E) {
    atomicAdd(&cnt_dst[edge_dst(ei, E, e, i64)], 1);
    atomicAdd(&cnt_src[edge_src(ei, E, e, i64)], 1);
  }
}

__global__ __launch_bounds__(1024) void scan_excl(
    const int* __restrict__ cnt, int* __restrict__ offs, int* __restrict__ cur,
    int n) {
  __shared__ int part[1024];
  int tid = threadIdx.x;
  int chunk = (n + 1023) >> 10;
  int b = tid * chunk;
  int e = min(b + chunk, n);
  int s = 0;
  for (int i = b; i < e; ++i) s += cnt[i];
  part[tid] = s;
  __syncthreads();
  for (int d = 1; d < 1024; d <<= 1) {
    int v = part[tid];
    int add = (tid >= d) ? part[tid - d] : 0;
    __syncthreads();
    part[tid] = v + add;
    __syncthreads();
  }
  int run = (tid == 0) ? 0 : part[tid - 1];
  for (int i = b; i < e; ++i) {
    offs[i] = run;
    cur[i] = run;
    run += cnt[i];
  }
  if (tid == 0) offs[n] = part[1023];
}

__global__ __launch_bounds__(256) void fill_edges(
    const int* __restrict__ ei, int E, const int* __restrict__ flags,
    int* __restrict__ cur1, int* __restrict__ srcs1, int* __restrict__ cur2,
    int* __restrict__ srcs2) {
  int i64 = flags[1];
  int e = blockIdx.x * blockDim.x + threadIdx.x;
  if (e < E) {
    int s = edge_src(ei, E, e, i64), d = edge_dst(ei, E, e, i64);
    int p = atomicAdd(&cur1[d], 1);
    srcs1[p] = s;
    int q = atomicAdd(&cur2[s], 1);
    srcs2[q] = d;
  }
}

// ---------------------------------------------------------------------------
// fused GAT: per-dst segment softmax (over a_j only), z accumulation,
// epilogue GEMM z @ Wr (head-mean) + residual + ELU (+ next-layer a_j)
// 256 threads, DPB dst nodes per block. Output is FLOAT32 (= d_out dtype).
// SRC_F32: source features are f32 (GAT2 reads updated h_mc from d_out)
// ---------------------------------------------------------------------------
template <bool WRITE_AJ, bool SRC_F32>
__global__ __launch_bounds__(256) void gat_fused(
    int Nd, const int* __restrict__ offs, const int* __restrict__ srcs,
    const float* __restrict__ aj, const void* __restrict__ h_src,
    const bf16* __restrict__ Wr, const bf16* __restrict__ h_res,
    float* __restrict__ out_f32, const float* __restrict__ vj_next,
    float* __restrict__ aj_next) {
  __shared__ float zbuf[DPB][512];
  __shared__ float abuf[EC][8];
  __shared__ int sbuf[EC];
  __shared__ float red[256];
  __shared__ float mj[8], sinv[8];

  int t = threadIdx.x;
  int h8 = t & 7;
  int wv = t >> 6;
  int lane = t & 63;
  int d0 = blockIdx.x * DPB;

  for (int dl = 0; dl < DPB; ++dl) {
    int d = d0 + dl;
    float z0 = 0.f, z1 = 0.f;
    if (d < Nd) {                       // uniform branch
      int beg = offs[d], end = offs[d + 1];
      int ne = end - beg;
      if (ne > 0) {                     // uniform branch
        // pass 1: per-head max of a_j over segment
        float lmax = -INFINITY;
        for (int p = t; p < ne * 8; p += 256) {
          int e = p >> 3;
          lmax = fmaxf(lmax, aj[(size_t)srcs[beg + e] * 8 + h8]);
        }
        red[t] = lmax;
        __syncthreads();
        if (t < 8) {
          float m = -INFINITY;
          for (int i = t; i < 256; i += 8) m = fmaxf(m, red[i]);
          mj[t] = m;
        }
        __syncthreads();
        // pass 2: per-head sum of exp
        float mjh = mj[h8];
        float lsum = 0.f;
        for (int p = t; p < ne * 8; p += 256) {
          int e = p >> 3;
          lsum += __expf(aj[(size_t)srcs[beg + e] * 8 + h8] - mjh);
        }
        red[t] = lsum;
        __syncthreads();
        if (t < 8) {
          float s = 0.f;
          for (int i = t; i < 256; i += 8) s += red[i];
          sinv[t] = 1.f / (s + 1e-16f);
        }
        __syncthreads();
        // pass 3: chunked weighted accumulation of raw source features
        for (int cb = 0; cb < ne; cb += EC) {
          int cn = min(EC, ne - cb);
          if (t < cn) sbuf[t] = srcs[beg + cb + t];
          __syncthreads();
          for (int p = t; p < cn * 8; p += 256) {
            int e = p >> 3, hh = p & 7;
            abuf[e][hh] = __expf(aj[(size_t)sbuf[e] * 8 + hh] - mj[hh]) * sinv[hh];
          }
          __syncthreads();
          for (int e = 0; e < cn; ++e) {
            size_t idx = (size_t)sbuf[e] * 64 + lane;
            float x = SRC_F32 ? ((const float*)h_src)[idx]
                              : __bfloat162float(((const bf16*)h_src)[idx]);
            z0 += abuf[e][wv] * x;
            z1 += abuf[e][wv + 4] * x;
          }
          __syncthreads();
        }
      }
    }
    zbuf[dl][t] = z0;
    zbuf[dl][t + 256] = z1;
  }
  __syncthreads();

  // epilogue GEMM: wave wv handles dsts d0 + wv*4 .. +3, lane = out channel
  float acc[4] = {0.f, 0.f, 0.f, 0.f};
  for (int k = 0; k < 512; ++k) {
    float w = __bfloat162float(Wr[k * 64 + lane]);
#pragma unroll
    for (int j = 0; j < 4; ++j) acc[j] += zbuf[wv * 4 + j][k] * w;
  }
#pragma unroll
  for (int j = 0; j < 4; ++j) {
    int d = d0 + wv * 4 + j;
    if (d < Nd) {                        // uniform per wave
      float v = __bfloat162float(h_res[(size_t)d * 64 + lane]) + 0.125f * acc[j];
      float o = v > 0.f ? v : expm1f(v);
      out_f32[(size_t)d * 64 + lane] = o;
      if (WRITE_AJ) {
#pragma unroll
        for (int hh = 0; hh < 8; ++hh) {
          float p = o * vj_next[hh * 64 + lane];
#pragma unroll
          for (int o2 = 32; o2 >= 1; o2 >>= 1) p += __shfl_xor(p, o2, 64);
          if (lane == 0) aj_next[(size_t)d * 8 + hh] = p;
        }
      }
    }
  }
}

// ---------------------------------------------------------------------------
extern "C" void kernel_launch(void* const* d_in, const int* in_sizes, int n_in,
                              void* d_out, int out_size, void* d_ws,
                              size_t ws_size, hipStream_t stream) {
  const void* op_nodes = d_in[0];
  const void* mc_nodes = d_in[1];
  const int* ei        = (const int*)d_in[2];
  const void* W_op     = d_in[3];
  const void* b_op     = d_in[4];
  const void* W_mc     = d_in[5];
  const void* b_mc     = d_in[6];
  const void* W_om     = d_in[7];
  const void* att_om   = d_in[8];
  const void* W_mo     = d_in[9];
  const void* att_mo   = d_in[10];

  int n_op = in_sizes[0] / 4;
  int n_mc = in_sizes[1] / 2;
  int E    = in_sizes[2] / 2;

  char* ws = (char*)d_ws;
  size_t off = 0;
  auto alloc = [&](size_t bytes) -> void* {
    void* p = ws + off;
    off = (off + bytes + 255) & ~(size_t)255;
    return p;
  };
  int* flags   = (int*)alloc(16);
  bf16* h_op   = (bf16*)alloc((size_t)n_op * 64 * 2);
  bf16* h_mc   = (bf16*)alloc((size_t)n_mc * 64 * 2);
  float* aj_op = (float*)alloc((size_t)n_op * 8 * 4);
  float* aj_mc = (float*)alloc((size_t)n_mc * 8 * 4);
  float* vj_om = (float*)alloc(512 * 4);
  float* vj_mo = (float*)alloc(512 * 4);
  bf16* Wr_om  = (bf16*)alloc(32768 * 2);
  bf16* Wr_mo  = (bf16*)alloc(32768 * 2);
  int* cnt1  = (int*)alloc((size_t)n_mc * 4);
  int* cnt2  = (int*)alloc((size_t)n_op * 4);
  int* offs1 = (int*)alloc((size_t)(n_mc + 1) * 4);
  int* cur1  = (int*)alloc((size_t)n_mc * 4);
  int* srcs1 = (int*)alloc((size_t)E * 4);
  int* offs2 = (int*)alloc((size_t)(n_op + 1) * 4);
  int* cur2  = (int*)alloc((size_t)n_op * 4);
  int* srcs2 = (int*)alloc((size_t)E * 4);

  float* out_op = (float*)d_out;                      // f32 output!
  float* out_mc = out_op + (size_t)n_op * 64;         // also layer-2 src (f32)

  hipMemsetAsync(cnt1, 0, (size_t)n_mc * 4, stream);
  hipMemsetAsync(cnt2, 0, (size_t)n_op * 4, stream);

  detect_kernel<<<1, 1024, 0, stream>>>(ei, (const unsigned short*)op_nodes, flags);

  prep_weights<<<128, 256, 0, stream>>>(W_om, att_om, flags, vj_om, Wr_om);
  prep_weights<<<128, 256, 0, stream>>>(W_mo, att_mo, flags, vj_mo, Wr_mo);

  node_transform<4><<<(n_op + 3) / 4, 256, 0, stream>>>(
      op_nodes, W_op, b_op, flags, vj_om, h_op, aj_op, n_op);
  node_transform<2><<<(n_mc + 3) / 4, 256, 0, stream>>>(
      mc_nodes, W_mc, b_mc, flags, (const float*)nullptr, h_mc, (float*)nullptr,
      n_mc);

  count_edges<<<(E + 255) / 256, 256, 0, stream>>>(ei, E, flags, cnt1, cnt2);
  scan_excl<<<1, 1024, 0, stream>>>(cnt1, offs1, cur1, n_mc);
  scan_excl<<<1, 1024, 0, stream>>>(cnt2, offs2, cur2, n_op);
  fill_edges<<<(E + 255) / 256, 256, 0, stream>>>(ei, E, flags, cur1, srcs1,
                                                  cur2, srcs2);

  // GAT1: op -> mc (writes out_mc f32 + a_j for layer 2)
  gat_fused<true, false><<<(n_mc + DPB - 1) / DPB, 256, 0, stream>>>(
      n_mc, offs1, srcs1, aj_op, h_op, Wr_om, h_mc, out_mc, vj_mo, aj_mc);
  // GAT2: mc -> op (src = layer-1 mc output, f32 in d_out)
  gat_fused<false, true><<<(n_op + DPB - 1) / DPB, 256, 0, stream>>>(
      n_op, offs2, srcs2, aj_mc, out_mc, Wr_mo, h_op, out_op,
      (const float*)nullptr, (float*)nullptr);
}

// Round 4
// 817.661 us; speedup vs baseline: 1.5110x; 1.5110x over previous
//
#include <hip/hip_runtime.h>
#include <hip/hip_bf16.h>

using bf16 = __hip_bfloat16;

// ---------------------------------------------------------------------------
// dual-dtype float load: is_f32 ? f32[i] : bf16[i]
// ---------------------------------------------------------------------------
__device__ __forceinline__ float loadf(const void* p, int i, int is_f32) {
  if (is_f32) return ((const float*)p)[i];
  return __bfloat162float(((const bf16*)p)[i]);
}

// ---------------------------------------------------------------------------
// detect input encodings by content (deterministic):
// flags[0] = floats are f32, flags[1] = edges are int64
// ---------------------------------------------------------------------------
__global__ __launch_bounds__(1024) void detect_kernel(
    const int* __restrict__ ei, const unsigned short* __restrict__ x,
    int* __restrict__ flags) {
  __shared__ int red[1024];
  int t = threadIdx.x;
  int o = 0;
  for (int i = t; i < 2048; i += 1024) o |= ei[2 * i + 1];
  int big = 0;
  for (int i = t; i < 2048; i += 1024) {
    float v = __uint_as_float(((unsigned)x[2 * i]) << 16);
    if (!(fabsf(v) < 1000.f)) big = 1;
  }
  red[t] = o;
  __syncthreads();
  for (int d = 512; d > 0; d >>= 1) {
    if (t < d) red[t] |= red[t + d];
    __syncthreads();
  }
  int o_all = red[0];
  __syncthreads();
  red[t] = big;
  __syncthreads();
  for (int d = 512; d > 0; d >>= 1) {
    if (t < d) red[t] |= red[t + d];
    __syncthreads();
  }
  if (t == 0) {
    flags[0] = red[0];
    flags[1] = (o_all == 0) ? 1 : 0;
  }
}

__device__ __forceinline__ int edge_src(const int* ei, int E, int e, int i64) {
  return i64 ? ei[2 * e] : ei[e];
}
__device__ __forceinline__ int edge_dst(const int* ei, int E, int e, int i64) {
  return i64 ? ei[2 * E + 2 * e] : ei[E + e];
}

// ---------------------------------------------------------------------------
// prep: vj[h*64+f] = sum_c att_j[h,c] * W[h*64+c, f]   (8x64 fp32)
//       Wr[(h*64+f)*64 + c] = W[(h*64+c)*64 + f]       (512x64 bf16)
// ---------------------------------------------------------------------------
__global__ __launch_bounds__(256) void prep_weights(
    const void* __restrict__ W, const void* __restrict__ att,
    const int* __restrict__ flags, float* __restrict__ vj,
    bf16* __restrict__ Wr) {
  int is_f32 = flags[0];
  int t = blockIdx.x * blockDim.x + threadIdx.x;
  if (t < 32768) {
    int c = t & 63, hf = t >> 6;
    int h = hf >> 6, f = hf & 63;
    Wr[t] = __float2bfloat16(loadf(W, ((h << 6) + c) * 64 + f, is_f32));
  }
  if (t < 512) {
    int hh = t >> 6, ff = t & 63;
    float s = 0.f;
    for (int cc = 0; cc < 64; ++cc)
      s += loadf(att, hh * 128 + 64 + cc, is_f32) *
           loadf(W, ((hh << 6) + cc) * 64 + ff, is_f32);
    vj[t] = s;
  }
}

// ---------------------------------------------------------------------------
// node transform: h = elu(x @ W.T + b) -> bf16, optional a_j = h . v_j
// ---------------------------------------------------------------------------
template <int FIN>
__global__ __launch_bounds__(256) void node_transform(
    const void* __restrict__ x, const void* __restrict__ W,
    const void* __restrict__ b, const int* __restrict__ flags,
    const float* __restrict__ vj, bf16* __restrict__ h_out,
    float* __restrict__ aj_out, int N) {
  int is_f32 = flags[0];
  int wave = threadIdx.x >> 6, lane = threadIdx.x & 63;
  int n = blockIdx.x * 4 + wave;
  if (n >= N) return;
  float acc = loadf(b, lane, is_f32);
#pragma unroll
  for (int f = 0; f < FIN; ++f)
    acc += loadf(x, n * FIN + f, is_f32) * loadf(W, lane * FIN + f, is_f32);
  float hv = acc > 0.f ? acc : expm1f(acc);
  h_out[(size_t)n * 64 + lane] = __float2bfloat16(hv);
  if (aj_out) {
#pragma unroll
    for (int hh = 0; hh < 8; ++hh) {
      float p = hv * vj[hh * 64 + lane];
#pragma unroll
      for (int o = 32; o >= 1; o >>= 1) p += __shfl_xor(p, o, 64);
      if (lane == 0) aj_out[(size_t)n * 8 + hh] = p;
    }
  }
}

// ---------------------------------------------------------------------------
// CSR build
// ---------------------------------------------------------------------------
__global__ __launch_bounds__(256) void count_edges(
    const int* __restrict__ ei, int E, const int* __restrict__ flags,
    int* __restrict__ cnt_dst, int* __restrict__ cnt_src) {
  int i64 = flags[1];
  int e = blockIdx.x * blockDim.x + threadIdx.x;
  if (e < E) {
    atomicAdd(&cnt_dst[edge_dst(ei, E, e, i64)], 1);
    atomicAdd(&cnt_src[edge_src(ei, E, e, i64)], 1);
  }
}

__global__ __launch_bounds__(1024) void scan_excl(
    const int* __restrict__ cnt, int* __restrict__ offs, int* __restrict__ cur,
    int n) {
  __shared__ int part[1024];
  int tid = threadIdx.x;
  int chunk = (n + 1023) >> 10;
  int b = tid * chunk;
  int e = min(b + chunk, n);
  int s = 0;
  for (int i = b; i < e; ++i) s += cnt[i];
  part[tid] = s;
  __syncthreads();
  for (int d = 1; d < 1024; d <<= 1) {
    int v = part[tid];
    int add = (tid >= d) ? part[tid - d] : 0;
    __syncthreads();
    part[tid] = v + add;
    __syncthreads();
  }
  int run = (tid == 0) ? 0 : part[tid - 1];
  for (int i = b; i < e; ++i) {
    offs[i] = run;
    cur[i] = run;
    run += cnt[i];
  }
  if (tid == 0) offs[n] = part[1023];
}

__global__ __launch_bounds__(256) void fill_edges(
    const int* __restrict__ ei, int E, const int* __restrict__ flags,
    int* __restrict__ cur1, int* __restrict__ srcs1, int* __restrict__ cur2,
    int* __restrict__ srcs2) {
  int i64 = flags[1];
  int e = blockIdx.x * blockDim.x + threadIdx.x;
  if (e < E) {
    int s = edge_src(ei, E, e, i64), d = edge_dst(ei, E, e, i64);
    int p = atomicAdd(&cur1[d], 1);
    srcs1[p] = s;
    int q = atomicAdd(&cur2[s], 1);
    srcs2[q] = d;
  }
}

// ---------------------------------------------------------------------------
// fused GAT, wave-synchronous (ZERO __syncthreads):
//   - each wave owns 4 consecutive dsts
//   - lane = (edge_slot e_l = lane>>3, head h_l = lane&7) for softmax
//   - online (m,s) per lane, guarded shfl_xor merge over the 8 edge slots
//   - z[4 dsts][8 heads] in VGPRs (lane = feature f)
//   - z -> LDS [wave][k=h*64+f][4] via ds_write_b128 (conflict-free)
//   - epilogue: 512-step GEMV, z broadcast b128 + Wr streamed once / 4 dsts
// ---------------------------------------------------------------------------
template <bool WRITE_AJ, bool SRC_F32>
__global__ __launch_bounds__(256) void gat_fused(
    int Nd, const int* __restrict__ offs, const int* __restrict__ srcs,
    const float* __restrict__ aj, const void* __restrict__ h_src,
    const bf16* __restrict__ Wr, const bf16* __restrict__ h_res,
    float* __restrict__ out_f32, const float* __restrict__ vj_next,
    float* __restrict__ aj_next) {
  __shared__ float zs[4][512][4];  // 32 KB

  int t = threadIdx.x;
  int wv = t >> 6;
  int lane = t & 63;
  int e_l = lane >> 3;  // edge slot 0..7
  int h_l = lane & 7;   // head
  int d0 = blockIdx.x * 16 + wv * 4;

  float z[4][8];
#pragma unroll
  for (int j = 0; j < 4; ++j)
#pragma unroll
    for (int h = 0; h < 8; ++h) z[j][h] = 0.f;

  for (int j = 0; j < 4; ++j) {
    int d = d0 + j;
    if (d >= Nd) break;                 // wave-uniform
    int beg = offs[d];
    int ne = offs[d + 1] - beg;
    if (ne == 0) continue;              // wave-uniform

    // --- pass A: online per-(slot,head) softmax stats ---
    float m = -INFINITY, s = 0.f;
    for (int c = 0; c < ne; c += 8) {
      int e = c + e_l;
      bool v = e < ne;
      int src = v ? srcs[beg + e] : 0;
      float a = v ? aj[(size_t)src * 8 + h_l] : 0.f;
      float mn = v ? fmaxf(m, a) : m;
      float sn = (s > 0.f ? s * __expf(m - mn) : 0.f) +
                 (v ? __expf(a - mn) : 0.f);
      m = mn;
      s = sn;
    }
    // merge the 8 edge slots (lanes differing in bits 3..5)
#pragma unroll
    for (int off = 8; off < 64; off <<= 1) {
      float mo = __shfl_xor(m, off, 64);
      float so = __shfl_xor(s, off, 64);
      float mn = fmaxf(m, mo);
      float sn = (s > 0.f ? s * __expf(m - mn) : 0.f) +
                 (so > 0.f ? so * __expf(mo - mn) : 0.f);
      m = mn;
      s = sn;
    }
    float sinv = 1.f / (s + 1e-16f);

    // --- pass B: weighted feature accumulation ---
    for (int c = 0; c < ne; c += 8) {
      int cn = min(8, ne - c);
      int e = c + e_l;
      bool v = e < ne;
      int src_l = v ? srcs[beg + e] : 0;
      float a = v ? aj[(size_t)src_l * 8 + h_l] : 0.f;
      float w = v ? __expf(a - m) * sinv : 0.f;
      for (int jj = 0; jj < cn; ++jj) {
        int srcj = __shfl(src_l, jj * 8, 64);
        size_t idx = (size_t)srcj * 64 + lane;
        float x = SRC_F32 ? ((const float*)h_src)[idx]
                          : __bfloat162float(((const bf16*)h_src)[idx]);
#pragma unroll
        for (int h = 0; h < 8; ++h)
          z[j][h] += __shfl(w, jj * 8 + h, 64) * x;
      }
    }
  }

  // --- z -> LDS, [wave][k][j] with packed float4 per (h) ---
#pragma unroll
  for (int h = 0; h < 8; ++h) {
    float4 zq = make_float4(z[0][h], z[1][h], z[2][h], z[3][h]);
    *((float4*)&zs[wv][h * 64 + lane][0]) = zq;
  }
  // wave-coherent LDS: compiler inserts lgkmcnt wait before reads; no barrier

  // --- epilogue GEMV: acc[j] = sum_k zs[wv][k][j] * Wr[k*64+lane] ---
  float acc[4] = {0.f, 0.f, 0.f, 0.f};
#pragma unroll 4
  for (int k = 0; k < 512; ++k) {
    float w = __bfloat162float(Wr[k * 64 + lane]);
    float4 zq = *((const float4*)&zs[wv][k][0]);
    acc[0] += zq.x * w;
    acc[1] += zq.y * w;
    acc[2] += zq.z * w;
    acc[3] += zq.w * w;
  }

#pragma unroll
  for (int j = 0; j < 4; ++j) {
    int d = d0 + j;
    if (d < Nd) {  // wave-uniform
      float v = __bfloat162float(h_res[(size_t)d * 64 + lane]) + 0.125f * acc[j];
      float o = v > 0.f ? v : expm1f(v);
      out_f32[(size_t)d * 64 + lane] = o;
      if (WRITE_AJ) {
#pragma unroll
        for (int hh = 0; hh < 8; ++hh) {
          float p = o * vj_next[hh * 64 + lane];
#pragma unroll
          for (int o2 = 32; o2 >= 1; o2 >>= 1) p += __shfl_xor(p, o2, 64);
          if (lane == 0) aj_next[(size_t)d * 8 + hh] = p;
        }
      }
    }
  }
}

// ---------------------------------------------------------------------------
extern "C" void kernel_launch(void* const* d_in, const int* in_sizes, int n_in,
                              void* d_out, int out_size, void* d_ws,
                              size_t ws_size, hipStream_t stream) {
  const void* op_nodes = d_in[0];
  const void* mc_nodes = d_in[1];
  const int* ei        = (const int*)d_in[2];
  const void* W_op     = d_in[3];
  const void* b_op     = d_in[4];
  const void* W_mc     = d_in[5];
  const void* b_mc     = d_in[6];
  const void* W_om     = d_in[7];
  const void* att_om   = d_in[8];
  const void* W_mo     = d_in[9];
  const void* att_mo   = d_in[10];

  int n_op = in_sizes[0] / 4;
  int n_mc = in_sizes[1] / 2;
  int E    = in_sizes[2] / 2;

  char* ws = (char*)d_ws;
  size_t off = 0;
  auto alloc = [&](size_t bytes) -> void* {
    void* p = ws + off;
    off = (off + bytes + 255) & ~(size_t)255;
    return p;
  };
  int* flags   = (int*)alloc(16);
  bf16* h_op   = (bf16*)alloc((size_t)n_op * 64 * 2);
  bf16* h_mc   = (bf16*)alloc((size_t)n_mc * 64 * 2);
  float* aj_op = (float*)alloc((size_t)n_op * 8 * 4);
  float* aj_mc = (float*)alloc((size_t)n_mc * 8 * 4);
  float* vj_om = (float*)alloc(512 * 4);
  float* vj_mo = (float*)alloc(512 * 4);
  bf16* Wr_om  = (bf16*)alloc(32768 * 2);
  bf16* Wr_mo  = (bf16*)alloc(32768 * 2);
  int* cnt1  = (int*)alloc((size_t)n_mc * 4);
  int* cnt2  = (int*)alloc((size_t)n_op * 4);
  int* offs1 = (int*)alloc((size_t)(n_mc + 1) * 4);
  int* cur1  = (int*)alloc((size_t)n_mc * 4);
  int* srcs1 = (int*)alloc((size_t)E * 4);
  int* offs2 = (int*)alloc((size_t)(n_op + 1) * 4);
  int* cur2  = (int*)alloc((size_t)n_op * 4);
  int* srcs2 = (int*)alloc((size_t)E * 4);

  float* out_op = (float*)d_out;
  float* out_mc = out_op + (size_t)n_op * 64;  // layer-1 result + layer-2 src

  hipMemsetAsync(cnt1, 0, (size_t)n_mc * 4, stream);
  hipMemsetAsync(cnt2, 0, (size_t)n_op * 4, stream);

  detect_kernel<<<1, 1024, 0, stream>>>(ei, (const unsigned short*)op_nodes, flags);

  prep_weights<<<128, 256, 0, stream>>>(W_om, att_om, flags, vj_om, Wr_om);
  prep_weights<<<128, 256, 0, stream>>>(W_mo, att_mo, flags, vj_mo, Wr_mo);

  node_transform<4><<<(n_op + 3) / 4, 256, 0, stream>>>(
      op_nodes, W_op, b_op, flags, vj_om, h_op, aj_op, n_op);
  node_transform<2><<<(n_mc + 3) / 4, 256, 0, stream>>>(
      mc_nodes, W_mc, b_mc, flags, (const float*)nullptr, h_mc, (float*)nullptr,
      n_mc);

  count_edges<<<(E + 255) / 256, 256, 0, stream>>>(ei, E, flags, cnt1, cnt2);
  scan_excl<<<1, 1024, 0, stream>>>(cnt1, offs1, cur1, n_mc);
  scan_excl<<<1, 1024, 0, stream>>>(cnt2, offs2, cur2, n_op);
  fill_edges<<<(E + 255) / 256, 256, 0, stream>>>(ei, E, flags, cur1, srcs1,
                                                  cur2, srcs2);

  // GAT1: op -> mc
  gat_fused<true, false><<<(n_mc + 15) / 16, 256, 0, stream>>>(
      n_mc, offs1, srcs1, aj_op, h_op, Wr_om, h_mc, out_mc, vj_mo, aj_mc);
  // GAT2: mc -> op
  gat_fused<false, true><<<(n_op + 15) / 16, 256, 0, stream>>>(
      n_op, offs2, srcs2, aj_mc, out_mc, Wr_mo, h_op, out_op,
      (const float*)nullptr, (float*)nullptr);
}

// Round 5
// 343.740 us; speedup vs baseline: 3.5942x; 2.3787x over previous
//
#include <hip/hip_runtime.h>
#include <hip/hip_bf16.h>

using bf16 = __hip_bfloat16;
typedef __attribute__((ext_vector_type(8))) short short8;
typedef __attribute__((ext_vector_type(4))) float f32x4;

__device__ __forceinline__ unsigned short f2bf(float f) {
  bf16 h = __float2bfloat16(f);
  return *reinterpret_cast<unsigned short*>(&h);
}

// ---------------------------------------------------------------------------
// dual-dtype float load: is_f32 ? f32[i] : bf16[i]
// ---------------------------------------------------------------------------
__device__ __forceinline__ float loadf(const void* p, int i, int is_f32) {
  if (is_f32) return ((const float*)p)[i];
  return __bfloat162float(((const bf16*)p)[i]);
}

// ---------------------------------------------------------------------------
// detect input encodings by content (deterministic):
// flags[0] = floats are f32, flags[1] = edges are int64
// ---------------------------------------------------------------------------
__global__ __launch_bounds__(1024) void detect_kernel(
    const int* __restrict__ ei, const unsigned short* __restrict__ x,
    int* __restrict__ flags) {
  __shared__ int red[1024];
  int t = threadIdx.x;
  int o = 0;
  for (int i = t; i < 2048; i += 1024) o |= ei[2 * i + 1];
  int big = 0;
  for (int i = t; i < 2048; i += 1024) {
    float v = __uint_as_float(((unsigned)x[2 * i]) << 16);
    if (!(fabsf(v) < 1000.f)) big = 1;
  }
  red[t] = o;
  __syncthreads();
  for (int d = 512; d > 0; d >>= 1) {
    if (t < d) red[t] |= red[t + d];
    __syncthreads();
  }
  int o_all = red[0];
  __syncthreads();
  red[t] = big;
  __syncthreads();
  for (int d = 512; d > 0; d >>= 1) {
    if (t < d) red[t] |= red[t + d];
    __syncthreads();
  }
  if (t == 0) {
    flags[0] = red[0];
    flags[1] = (o_all == 0) ? 1 : 0;
  }
}

__device__ __forceinline__ int edge_src(const int* ei, int E, int e, int i64) {
  return i64 ? ei[2 * e] : ei[e];
}
__device__ __forceinline__ int edge_dst(const int* ei, int E, int e, int i64) {
  return i64 ? ei[2 * E + 2 * e] : ei[E + e];
}

// ---------------------------------------------------------------------------
// prep: vj[h*64+f] = sum_c att_j[h,c] * W[h*64+c, f]       (8x64 fp32)
//       Wrt[c*512 + k'] = W[(h*64+c)*64 + f], k' = f*8+h   (64x512 bf16)
// ---------------------------------------------------------------------------
__global__ __launch_bounds__(256) void prep_weights(
    const void* __restrict__ W, const void* __restrict__ att,
    const int* __restrict__ flags, float* __restrict__ vj,
    bf16* __restrict__ Wrt) {
  int is_f32 = flags[0];
  int t = blockIdx.x * blockDim.x + threadIdx.x;
  if (t < 32768) {
    int c = t >> 9, k = t & 511;
    int f = k >> 3, h = k & 7;
    Wrt[t] = __float2bfloat16(loadf(W, ((h << 6) + c) * 64 + f, is_f32));
  }
  if (t < 512) {
    int hh = t >> 6, ff = t & 63;
    float s = 0.f;
    for (int cc = 0; cc < 64; ++cc)
      s += loadf(att, hh * 128 + 64 + cc, is_f32) *
           loadf(W, ((hh << 6) + cc) * 64 + ff, is_f32);
    vj[t] = s;
  }
}

// ---------------------------------------------------------------------------
// node transform: h = elu(x @ W.T + b) -> bf16, optional a_j = h . v_j
// ---------------------------------------------------------------------------
template <int FIN>
__global__ __launch_bounds__(256) void node_transform(
    const void* __restrict__ x, const void* __restrict__ W,
    const void* __restrict__ b, const int* __restrict__ flags,
    const float* __restrict__ vj, bf16* __restrict__ h_out,
    float* __restrict__ aj_out, int N) {
  int is_f32 = flags[0];
  int wave = threadIdx.x >> 6, lane = threadIdx.x & 63;
  int n = blockIdx.x * 4 + wave;
  if (n >= N) return;
  float acc = loadf(b, lane, is_f32);
#pragma unroll
  for (int f = 0; f < FIN; ++f)
    acc += loadf(x, n * FIN + f, is_f32) * loadf(W, lane * FIN + f, is_f32);
  float hv = acc > 0.f ? acc : expm1f(acc);
  h_out[(size_t)n * 64 + lane] = __float2bfloat16(hv);
  if (aj_out) {
#pragma unroll
    for (int hh = 0; hh < 8; ++hh) {
      float p = hv * vj[hh * 64 + lane];
#pragma unroll
      for (int o = 32; o >= 1; o >>= 1) p += __shfl_xor(p, o, 64);
      if (lane == 0) aj_out[(size_t)n * 8 + hh] = p;
    }
  }
}

// ---------------------------------------------------------------------------
// CSR build: count, 3-kernel parallel exclusive scan, fill
// ---------------------------------------------------------------------------
__global__ __launch_bounds__(256) void count_edges(
    const int* __restrict__ ei, int E, const int* __restrict__ flags,
    int* __restrict__ cnt_dst, int* __restrict__ cnt_src) {
  int i64 = flags[1];
  int e = blockIdx.x * blockDim.x + threadIdx.x;
  if (e < E) {
    atomicAdd(&cnt_dst[edge_dst(ei, E, e, i64)], 1);
    atomicAdd(&cnt_src[edge_src(ei, E, e, i64)], 1);
  }
}

__global__ __launch_bounds__(256) void scan_bsum(
    const int* __restrict__ cnt, int n, int* __restrict__ bsum) {
  __shared__ int red[256];
  int t = threadIdx.x;
  int base = blockIdx.x * 2048 + t * 8;
  int s = 0;
#pragma unroll
  for (int i = 0; i < 8; ++i)
    if (base + i < n) s += cnt[base + i];
  red[t] = s;
  __syncthreads();
  for (int d = 128; d > 0; d >>= 1) {
    if (t < d) red[t] += red[t + d];
    __syncthreads();
  }
  if (t == 0) bsum[blockIdx.x] = red[0];
}

__global__ __launch_bounds__(64) void scan_btop(
    const int* __restrict__ bsum, int nb, int* __restrict__ bscan,
    int* __restrict__ offs, int n) {
  if (threadIdx.x == 0) {
    int run = 0;
    for (int b = 0; b < nb; ++b) {
      bscan[b] = run;
      run += bsum[b];
    }
    offs[n] = run;
  }
}

__global__ __launch_bounds__(256) void scan_write(
    const int* __restrict__ cnt, int n, const int* __restrict__ bscan,
    int* __restrict__ offs, int* __restrict__ cur) {
  __shared__ int red[256];
  int t = threadIdx.x;
  int base = blockIdx.x * 2048 + t * 8;
  int c[8];
  int s = 0;
#pragma unroll
  for (int i = 0; i < 8; ++i) {
    c[i] = (base + i < n) ? cnt[base + i] : 0;
    s += c[i];
  }
  red[t] = s;
  __syncthreads();
  // inclusive Hillis-Steele over thread totals
  for (int d = 1; d < 256; d <<= 1) {
    int v = red[t];
    int add = (t >= d) ? red[t - d] : 0;
    __syncthreads();
    red[t] = v + add;
    __syncthreads();
  }
  int run = bscan[blockIdx.x] + red[t] - s;  // exclusive base for this thread
#pragma unroll
  for (int i = 0; i < 8; ++i) {
    if (base + i < n) {
      offs[base + i] = run;
      cur[base + i] = run;
      run += c[i];
    }
  }
}

__global__ __launch_bounds__(256) void fill_edges(
    const int* __restrict__ ei, int E, const int* __restrict__ flags,
    int* __restrict__ cur1, int* __restrict__ srcs1, int* __restrict__ cur2,
    int* __restrict__ srcs2) {
  int i64 = flags[1];
  int e = blockIdx.x * blockDim.x + threadIdx.x;
  if (e < E) {
    int s = edge_src(ei, E, e, i64), d = edge_dst(ei, E, e, i64);
    int p = atomicAdd(&cur1[d], 1);
    srcs1[p] = s;
    int q = atomicAdd(&cur2[s], 1);
    srcs2[q] = d;
  }
}

// ---------------------------------------------------------------------------
// fused GAT: wave-sync gather (4 dsts/wave, online softmax in-lane) producing
// z[16 dsts][512] bf16 in LDS (k' = f*8+h, row stride 520 vs bank conflicts),
// then block-level MFMA epilogue: each wave one 16x16 slice of the 16x64
// output via 16x mfma_f32_16x16x32_bf16 (A from LDS, B = Wrt from global),
// + residual + ELU (+ next-layer a_j via cross-wave partial sums).
// ---------------------------------------------------------------------------
template <bool WRITE_AJ, bool SRC_F32>
__global__ __launch_bounds__(256) void gat_fused(
    int Nd, const int* __restrict__ offs, const int* __restrict__ srcs,
    const float* __restrict__ aj, const void* __restrict__ h_src,
    const bf16* __restrict__ Wrt, const bf16* __restrict__ h_res,
    float* __restrict__ out_f32, const float* __restrict__ vj_next,
    float* __restrict__ aj_next) {
  __shared__ __align__(16) unsigned short Zl[16 * 520];  // 16.6 KB
  __shared__ float ajp[4][16][8];                        // 2 KB

  int t = threadIdx.x;
  int wv = t >> 6;
  int lane = t & 63;
  int e_l = lane >> 3;  // edge slot 0..7
  int h_l = lane & 7;   // head
  int d0 = blockIdx.x * 16;
  int d0w = d0 + wv * 4;

  float z[4][8];
#pragma unroll
  for (int j = 0; j < 4; ++j)
#pragma unroll
    for (int h = 0; h < 8; ++h) z[j][h] = 0.f;

  for (int j = 0; j < 4; ++j) {
    int d = d0w + j;
    if (d >= Nd) break;                 // wave-uniform
    int beg = offs[d];
    int ne = offs[d + 1] - beg;
    if (ne == 0) continue;              // wave-uniform

    // --- pass A: online per-(slot,head) softmax stats, then slot merge ---
    float m = -INFINITY, s = 0.f;
    for (int c = 0; c < ne; c += 8) {
      int e = c + e_l;
      bool v = e < ne;
      int src = v ? srcs[beg + e] : 0;
      float a = v ? aj[(size_t)src * 8 + h_l] : 0.f;
      float mn = v ? fmaxf(m, a) : m;
      float sn = (s > 0.f ? s * __expf(m - mn) : 0.f) +
                 (v ? __expf(a - mn) : 0.f);
      m = mn;
      s = sn;
    }
#pragma unroll
    for (int off = 8; off < 64; off <<= 1) {
      float mo = __shfl_xor(m, off, 64);
      float so = __shfl_xor(s, off, 64);
      float mn = fmaxf(m, mo);
      float sn = (s > 0.f ? s * __expf(m - mn) : 0.f) +
                 (so > 0.f ? so * __expf(mo - mn) : 0.f);
      m = mn;
      s = sn;
    }
    float sinv = 1.f / (s + 1e-16f);

    // --- pass B: weighted feature accumulation ---
    for (int c = 0; c < ne; c += 8) {
      int cn = min(8, ne - c);
      int e = c + e_l;
      bool v = e < ne;
      int src_l = v ? srcs[beg + e] : 0;
      float a = v ? aj[(size_t)src_l * 8 + h_l] : 0.f;
      float w = v ? __expf(a - m) * sinv : 0.f;
      for (int jj = 0; jj < cn; ++jj) {
        int srcj = __shfl(src_l, jj * 8, 64);
        size_t idx = (size_t)srcj * 64 + lane;
        float x = SRC_F32 ? ((const float*)h_src)[idx]
                          : __bfloat162float(((const bf16*)h_src)[idx]);
#pragma unroll
        for (int h = 0; h < 8; ++h)
          z[j][h] += __shfl(w, jj * 8 + h, 64) * x;
      }
    }
  }

  // --- z -> LDS bf16: row = wv*4+j, elems k' = lane*8 + h (16B per store) ---
#pragma unroll
  for (int j = 0; j < 4; ++j) {
    int4 pk;
    pk.x = ((int)f2bf(z[j][1]) << 16) | f2bf(z[j][0]);
    pk.y = ((int)f2bf(z[j][3]) << 16) | f2bf(z[j][2]);
    pk.z = ((int)f2bf(z[j][5]) << 16) | f2bf(z[j][4]);
    pk.w = ((int)f2bf(z[j][7]) << 16) | f2bf(z[j][6]);
    *(int4*)&Zl[(wv * 4 + j) * 520 + lane * 8] = pk;
  }
  __syncthreads();

  // --- MFMA epilogue: wave wv computes rows 0..15, cols wv*16..wv*16+15 ---
  int row = lane & 15;   // A row / B col / D col
  int kg = lane >> 4;    // 0..3
  f32x4 acc = {0.f, 0.f, 0.f, 0.f};
#pragma unroll
  for (int kt = 0; kt < 16; ++kt) {
    int kbase = kt * 32 + kg * 8;
    short8 a = *(const short8*)&Zl[row * 520 + kbase];
    short8 b = *(const short8*)&Wrt[(size_t)(wv * 16 + row) * 512 + kbase];
    acc = __builtin_amdgcn_mfma_f32_16x16x32_bf16(a, b, acc, 0, 0, 0);
  }

  int col = wv * 16 + row;
  float o_r[4];
#pragma unroll
  for (int r = 0; r < 4; ++r) {
    int dloc = kg * 4 + r;
    int d = d0 + dloc;
    float o = 0.f;
    if (d < Nd) {
      float v = __bfloat162float(h_res[(size_t)d * 64 + col]) + 0.125f * acc[r];
      o = v > 0.f ? v : expm1f(v);
      out_f32[(size_t)d * 64 + col] = o;
    }
    o_r[r] = o;
  }

  if (WRITE_AJ) {
#pragma unroll
    for (int r = 0; r < 4; ++r) {
      int dloc = kg * 4 + r;
#pragma unroll
      for (int h = 0; h < 8; ++h) {
        float p = o_r[r] * vj_next[h * 64 + col];
        p += __shfl_xor(p, 1, 64);
        p += __shfl_xor(p, 2, 64);
        p += __shfl_xor(p, 4, 64);
        p += __shfl_xor(p, 8, 64);
        if (row == 0) ajp[wv][dloc][h] = p;
      }
    }
    __syncthreads();
    if (t < 128) {
      int dloc = t >> 3, h = t & 7;
      int d = d0 + dloc;
      if (d < Nd) {
        float s = ajp[0][dloc][h] + ajp[1][dloc][h] + ajp[2][dloc][h] +
                  ajp[3][dloc][h];
        aj_next[(size_t)d * 8 + h] = s;
      }
    }
  }
}

// ---------------------------------------------------------------------------
extern "C" void kernel_launch(void* const* d_in, const int* in_sizes, int n_in,
                              void* d_out, int out_size, void* d_ws,
                              size_t ws_size, hipStream_t stream) {
  const void* op_nodes = d_in[0];
  const void* mc_nodes = d_in[1];
  const int* ei        = (const int*)d_in[2];
  const void* W_op     = d_in[3];
  const void* b_op     = d_in[4];
  const void* W_mc     = d_in[5];
  const void* b_mc     = d_in[6];
  const void* W_om     = d_in[7];
  const void* att_om   = d_in[8];
  const void* W_mo     = d_in[9];
  const void* att_mo   = d_in[10];

  int n_op = in_sizes[0] / 4;
  int n_mc = in_sizes[1] / 2;
  int E    = in_sizes[2] / 2;

  char* ws = (char*)d_ws;
  size_t off = 0;
  auto alloc = [&](size_t bytes) -> void* {
    void* p = ws + off;
    off = (off + bytes + 255) & ~(size_t)255;
    return p;
  };
  int* flags   = (int*)alloc(16);
  bf16* h_op   = (bf16*)alloc((size_t)n_op * 64 * 2);
  bf16* h_mc   = (bf16*)alloc((size_t)n_mc * 64 * 2);
  float* aj_op = (float*)alloc((size_t)n_op * 8 * 4);
  float* aj_mc = (float*)alloc((size_t)n_mc * 8 * 4);
  float* vj_om = (float*)alloc(512 * 4);
  float* vj_mo = (float*)alloc(512 * 4);
  bf16* Wrt_om = (bf16*)alloc(32768 * 2);
  bf16* Wrt_mo = (bf16*)alloc(32768 * 2);
  int* cnt1  = (int*)alloc((size_t)n_mc * 4);
  int* cnt2  = (int*)alloc((size_t)n_op * 4);
  int* offs1 = (int*)alloc((size_t)(n_mc + 1) * 4);
  int* cur1  = (int*)alloc((size_t)n_mc * 4);
  int* srcs1 = (int*)alloc((size_t)E * 4);
  int* offs2 = (int*)alloc((size_t)(n_op + 1) * 4);
  int* cur2  = (int*)alloc((size_t)n_op * 4);
  int* srcs2 = (int*)alloc((size_t)E * 4);
  int* bsum  = (int*)alloc(64 * 4);
  int* bscan = (int*)alloc(64 * 4);

  float* out_op = (float*)d_out;
  float* out_mc = out_op + (size_t)n_op * 64;  // layer-1 result + layer-2 src

  hipMemsetAsync(cnt1, 0, (size_t)n_mc * 4, stream);
  hipMemsetAsync(cnt2, 0, (size_t)n_op * 4, stream);

  detect_kernel<<<1, 1024, 0, stream>>>(ei, (const unsigned short*)op_nodes, flags);

  prep_weights<<<128, 256, 0, stream>>>(W_om, att_om, flags, vj_om, Wrt_om);
  prep_weights<<<128, 256, 0, stream>>>(W_mo, att_mo, flags, vj_mo, Wrt_mo);

  node_transform<4><<<(n_op + 3) / 4, 256, 0, stream>>>(
      op_nodes, W_op, b_op, flags, vj_om, h_op, aj_op, n_op);
  node_transform<2><<<(n_mc + 3) / 4, 256, 0, stream>>>(
      mc_nodes, W_mc, b_mc, flags, (const float*)nullptr, h_mc, (float*)nullptr,
      n_mc);

  count_edges<<<(E + 255) / 256, 256, 0, stream>>>(ei, E, flags, cnt1, cnt2);

  int nb1 = (n_mc + 2047) / 2048, nb2 = (n_op + 2047) / 2048;
  scan_bsum<<<nb1, 256, 0, stream>>>(cnt1, n_mc, bsum);
  scan_btop<<<1, 64, 0, stream>>>(bsum, nb1, bscan, offs1, n_mc);
  scan_write<<<nb1, 256, 0, stream>>>(cnt1, n_mc, bscan, offs1, cur1);
  scan_bsum<<<nb2, 256, 0, stream>>>(cnt2, n_op, bsum);
  scan_btop<<<1, 64, 0, stream>>>(bsum, nb2, bscan, offs2, n_op);
  scan_write<<<nb2, 256, 0, stream>>>(cnt2, n_op, bscan, offs2, cur2);

  fill_edges<<<(E + 255) / 256, 256, 0, stream>>>(ei, E, flags, cur1, srcs1,
                                                  cur2, srcs2);

  // GAT1: op -> mc (writes out_mc f32 + aj_mc for layer 2)
  gat_fused<true, false><<<(n_mc + 15) / 16, 256, 0, stream>>>(
      n_mc, offs1, srcs1, aj_op, h_op, Wrt_om, h_mc, out_mc, vj_mo, aj_mc);
  // GAT2: mc -> op (src = layer-1 mc output, f32 in d_out)
  gat_fused<false, true><<<(n_op + 15) / 16, 256, 0, stream>>>(
      n_op, offs2, srcs2, aj_mc, out_mc, Wrt_mo, h_op, out_op,
      (const float*)nullptr, (float*)nullptr);
}

// Round 6
// 333.584 us; speedup vs baseline: 3.7036x; 1.0304x over previous
//
#include <hip/hip_runtime.h>
#include <hip/hip_bf16.h>

using bf16 = __hip_bfloat16;
typedef __attribute__((ext_vector_type(8))) short short8;
typedef __attribute__((ext_vector_type(4))) float f32x4;

__device__ __forceinline__ unsigned short f2bf(float f) {
  bf16 h = __float2bfloat16(f);
  return *reinterpret_cast<unsigned short*>(&h);
}

__device__ __forceinline__ float loadf(const void* p, int i, int is_f32) {
  if (is_f32) return ((const float*)p)[i];
  return __bfloat162float(((const bf16*)p)[i]);
}

// ---------------------------------------------------------------------------
// detect input encodings by content (deterministic):
// flags[0] = floats are f32, flags[1] = edges are int64
// ---------------------------------------------------------------------------
__global__ __launch_bounds__(1024) void detect_kernel(
    const int* __restrict__ ei, const unsigned short* __restrict__ x,
    int* __restrict__ flags) {
  __shared__ int red[1024];
  int t = threadIdx.x;
  int o = 0;
  for (int i = t; i < 2048; i += 1024) o |= ei[2 * i + 1];
  int big = 0;
  for (int i = t; i < 2048; i += 1024) {
    float v = __uint_as_float(((unsigned)x[2 * i]) << 16);
    if (!(fabsf(v) < 1000.f)) big = 1;
  }
  red[t] = o;
  __syncthreads();
  for (int d = 512; d > 0; d >>= 1) {
    if (t < d) red[t] |= red[t + d];
    __syncthreads();
  }
  int o_all = red[0];
  __syncthreads();
  red[t] = big;
  __syncthreads();
  for (int d = 512; d > 0; d >>= 1) {
    if (t < d) red[t] |= red[t + d];
    __syncthreads();
  }
  if (t == 0) {
    flags[0] = red[0];
    flags[1] = (o_all == 0) ? 1 : 0;
  }
}

__device__ __forceinline__ int edge_src(const int* ei, int E, int e, int i64) {
  return i64 ? ei[2 * e] : ei[e];
}
__device__ __forceinline__ int edge_dst(const int* ei, int E, int e, int i64) {
  return i64 ? ei[2 * E + 2 * e] : ei[E + e];
}

// ---------------------------------------------------------------------------
// prep (both layers in one launch):
//   vj[h*64+f] = sum_c att_j[h,c] * W[h*64+c, f]       (8x64 fp32)
//   Wrt[c*512 + k'] = W[(h*64+c)*64 + f], k' = f*8+h   (64x512 bf16)
// ---------------------------------------------------------------------------
__global__ __launch_bounds__(256) void prep_all(
    const void* __restrict__ W1, const void* __restrict__ att1,
    const void* __restrict__ W2, const void* __restrict__ att2,
    const int* __restrict__ flags, float* __restrict__ vj1,
    bf16* __restrict__ Wrt1, float* __restrict__ vj2,
    bf16* __restrict__ Wrt2) {
  int is_f32 = flags[0];
  int side = blockIdx.x >= 128;
  const void* W = side ? W2 : W1;
  const void* att = side ? att2 : att1;
  float* vj = side ? vj2 : vj1;
  bf16* Wrt = side ? Wrt2 : Wrt1;
  int t = (blockIdx.x & 127) * 256 + threadIdx.x;
  if (t < 32768) {
    int c = t >> 9, k = t & 511;
    int f = k >> 3, h = k & 7;
    Wrt[t] = __float2bfloat16(loadf(W, ((h << 6) + c) * 64 + f, is_f32));
  }
  if (t < 512) {
    int hh = t >> 6, ff = t & 63;
    float s = 0.f;
    for (int cc = 0; cc < 64; ++cc)
      s += loadf(att, hh * 128 + 64 + cc, is_f32) *
           loadf(W, ((hh << 6) + cc) * 64 + ff, is_f32);
    vj[t] = s;
  }
}

// ---------------------------------------------------------------------------
// node transform (both node sets in one launch): h = elu(x@W.T+b) -> bf16,
// op side also computes a_j = h . v_j per head
// ---------------------------------------------------------------------------
template <int FIN>
__device__ __forceinline__ void node_body(
    const void* x, const void* W, const void* b, int is_f32,
    const float* vj, bf16* h_out, float* aj_out, int n) {
  int lane = threadIdx.x & 63;
  float acc = loadf(b, lane, is_f32);
#pragma unroll
  for (int f = 0; f < FIN; ++f)
    acc += loadf(x, n * FIN + f, is_f32) * loadf(W, lane * FIN + f, is_f32);
  float hv = acc > 0.f ? acc : expm1f(acc);
  h_out[(size_t)n * 64 + lane] = __float2bfloat16(hv);
  if (aj_out) {
#pragma unroll
    for (int hh = 0; hh < 8; ++hh) {
      float p = hv * vj[hh * 64 + lane];
#pragma unroll
      for (int o = 32; o >= 1; o >>= 1) p += __shfl_xor(p, o, 64);
      if (lane == 0) aj_out[(size_t)n * 8 + hh] = p;
    }
  }
}

__global__ __launch_bounds__(256) void node_all(
    const void* __restrict__ x_op, const void* __restrict__ W_op,
    const void* __restrict__ b_op, const void* __restrict__ x_mc,
    const void* __restrict__ W_mc, const void* __restrict__ b_mc,
    const int* __restrict__ flags, const float* __restrict__ vj,
    bf16* __restrict__ h_op, float* __restrict__ aj_op,
    bf16* __restrict__ h_mc, int n_op, int n_mc, int nbo) {
  int is_f32 = flags[0];
  int wave = threadIdx.x >> 6;
  if ((int)blockIdx.x < nbo) {
    int n = blockIdx.x * 4 + wave;
    if (n < n_op) node_body<4>(x_op, W_op, b_op, is_f32, vj, h_op, aj_op, n);
  } else {
    int n = (blockIdx.x - nbo) * 4 + wave;
    if (n < n_mc)
      node_body<2>(x_mc, W_mc, b_mc, is_f32, nullptr, h_mc, nullptr, n);
  }
}

// ---------------------------------------------------------------------------
// CSR build: count, 3-stage parallel exclusive scan (both sides merged), fill
// ---------------------------------------------------------------------------
__global__ __launch_bounds__(256) void count_edges(
    const int* __restrict__ ei, int E, const int* __restrict__ flags,
    int* __restrict__ cnt_dst, int* __restrict__ cnt_src) {
  int i64 = flags[1];
  int e = blockIdx.x * blockDim.x + threadIdx.x;
  if (e < E) {
    atomicAdd(&cnt_dst[edge_dst(ei, E, e, i64)], 1);
    atomicAdd(&cnt_src[edge_src(ei, E, e, i64)], 1);
  }
}

__global__ __launch_bounds__(256) void scan_bsum2(
    const int* __restrict__ cnt1, int n1, int nb1, const int* __restrict__ cnt2,
    int n2, int* __restrict__ bsum1, int* __restrict__ bsum2) {
  __shared__ int red[256];
  int t = threadIdx.x;
  int side = (int)blockIdx.x >= nb1;
  const int* cnt = side ? cnt2 : cnt1;
  int n = side ? n2 : n1;
  int blk = side ? (blockIdx.x - nb1) : blockIdx.x;
  int base = blk * 2048 + t * 8;
  int s = 0;
#pragma unroll
  for (int i = 0; i < 8; ++i)
    if (base + i < n) s += cnt[base + i];
  red[t] = s;
  __syncthreads();
  for (int d = 128; d > 0; d >>= 1) {
    if (t < d) red[t] += red[t + d];
    __syncthreads();
  }
  if (t == 0) (side ? bsum2 : bsum1)[blk] = red[0];
}

__global__ __launch_bounds__(128) void scan_btop2(
    const int* __restrict__ bsum1, int nb1, int* __restrict__ bscan1,
    int* __restrict__ offs1, int n1, const int* __restrict__ bsum2, int nb2,
    int* __restrict__ bscan2, int* __restrict__ offs2, int n2) {
  int t = threadIdx.x;
  if (t == 0) {
    int run = 0;
    for (int b = 0; b < nb1; ++b) {
      bscan1[b] = run;
      run += bsum1[b];
    }
    offs1[n1] = run;
  }
  if (t == 64) {
    int run = 0;
    for (int b = 0; b < nb2; ++b) {
      bscan2[b] = run;
      run += bsum2[b];
    }
    offs2[n2] = run;
  }
}

__global__ __launch_bounds__(256) void scan_write2(
    const int* __restrict__ cnt1, int n1, int nb1,
    const int* __restrict__ bscan1, int* __restrict__ offs1,
    int* __restrict__ cur1, const int* __restrict__ cnt2, int n2,
    const int* __restrict__ bscan2, int* __restrict__ offs2,
    int* __restrict__ cur2) {
  __shared__ int red[256];
  int t = threadIdx.x;
  int side = (int)blockIdx.x >= nb1;
  const int* cnt = side ? cnt2 : cnt1;
  const int* bscan = side ? bscan2 : bscan1;
  int* offs = side ? offs2 : offs1;
  int* cur = side ? cur2 : cur1;
  int n = side ? n2 : n1;
  int blk = side ? (blockIdx.x - nb1) : blockIdx.x;
  int base = blk * 2048 + t * 8;
  int c[8];
  int s = 0;
#pragma unroll
  for (int i = 0; i < 8; ++i) {
    c[i] = (base + i < n) ? cnt[base + i] : 0;
    s += c[i];
  }
  red[t] = s;
  __syncthreads();
  for (int d = 1; d < 256; d <<= 1) {
    int v = red[t];
    int add = (t >= d) ? red[t - d] : 0;
    __syncthreads();
    red[t] = v + add;
    __syncthreads();
  }
  int run = bscan[blk] + red[t] - s;
#pragma unroll
  for (int i = 0; i < 8; ++i) {
    if (base + i < n) {
      offs[base + i] = run;
      cur[base + i] = run;
      run += c[i];
    }
  }
}

__global__ __launch_bounds__(256) void fill_edges(
    const int* __restrict__ ei, int E, const int* __restrict__ flags,
    int* __restrict__ cur1, int* __restrict__ srcs1, int* __restrict__ cur2,
    int* __restrict__ srcs2) {
  int i64 = flags[1];
  int e = blockIdx.x * blockDim.x + threadIdx.x;
  if (e < E) {
    int s = edge_src(ei, E, e, i64), d = edge_dst(ei, E, e, i64);
    int p = atomicAdd(&cur1[d], 1);
    srcs1[p] = s;
    int q = atomicAdd(&cur2[s], 1);
    srcs2[q] = d;
  }
}

// ---------------------------------------------------------------------------
// gat_stats: dst-parallel segment softmax. lane=(dst_slot 0..7, head 0..7),
// 8 dsts/wave, 32 dsts/block. Writes normalized per-edge weights ew[e][8].
// ---------------------------------------------------------------------------
__global__ __launch_bounds__(256) void gat_stats(
    int Nd, const int* __restrict__ offs, const int* __restrict__ srcs,
    const float* __restrict__ aj, float* __restrict__ ew) {
  int t = threadIdx.x;
  int wv = t >> 6, lane = t & 63;
  int slot = lane >> 3, h = lane & 7;
  int d = blockIdx.x * 32 + wv * 8 + slot;
  if (d >= Nd) return;
  int beg = offs[d], ne = offs[d + 1] - beg;
  if (ne == 0) return;
  float m = -INFINITY, s = 0.f;
  for (int e = 0; e < ne; ++e) {
    float a = aj[(size_t)srcs[beg + e] * 8 + h];
    float mn = fmaxf(m, a);
    s = s * __expf(m - mn) + __expf(a - mn);
    m = mn;
  }
  float sinv = 1.f / (s + 1e-16f);
  for (int e = 0; e < ne; ++e) {
    float a = aj[(size_t)srcs[beg + e] * 8 + h];
    ew[(size_t)(beg + e) * 8 + h] = __expf(a - m) * sinv;
  }
}

// ---------------------------------------------------------------------------
// gat_gather: 4 dsts/wave, 16 dsts/block. Stage srcs+ew chunks in LDS,
// per edge: 1 coalesced h_src row load + 8 LDS-broadcast + 8 fma.
// Epilogue: block MFMA (16x512 @ 512x64) + residual + ELU (+ aj_next).
// ---------------------------------------------------------------------------
template <bool WRITE_AJ, bool SRC_F32>
__global__ __launch_bounds__(256) void gat_gather(
    int Nd, const int* __restrict__ offs, const int* __restrict__ srcs,
    const float* __restrict__ ew, const void* __restrict__ h_src,
    const bf16* __restrict__ Wrt, const bf16* __restrict__ h_res,
    float* __restrict__ out_f32, const float* __restrict__ vj_next,
    float* __restrict__ aj_next) {
  __shared__ __align__(16) unsigned short Zl[16 * 520];  // 16.3 KB
  __shared__ float ajp[4][16][8];                        // 2 KB
  __shared__ int srcs_s[4][32];
  __shared__ float ew_s[4][256];

  int t = threadIdx.x;
  int wv = t >> 6, lane = t & 63;
  int d0 = blockIdx.x * 16;
  int dlo = d0 + wv * 4;

  float z[4][8];
#pragma unroll
  for (int j = 0; j < 4; ++j)
#pragma unroll
    for (int h = 0; h < 8; ++h) z[j][h] = 0.f;

  if (dlo < Nd) {
    int o[5];
#pragma unroll
    for (int j = 0; j <= 4; ++j) o[j] = offs[min(dlo + j, Nd)];
    int beg = o[0], end = o[4];
    for (int cb = beg; cb < end; cb += 32) {
      int cn = min(32, end - cb);
      if (lane < cn) srcs_s[wv][lane] = srcs[cb + lane];
      for (int i = lane; i < cn * 8; i += 64)
        ew_s[wv][i] = ew[(size_t)cb * 8 + i];
      asm volatile("s_waitcnt lgkmcnt(0)" ::: "memory");
#pragma unroll
      for (int j = 0; j < 4; ++j) {
        int elo = max(cb, o[j]) - cb, ehi = min(cb + cn, o[j + 1]) - cb;
        for (int i = elo; i < ehi; ++i) {
          int src = srcs_s[wv][i];
          size_t idx = (size_t)src * 64 + lane;
          float x = SRC_F32 ? ((const float*)h_src)[idx]
                            : __bfloat162float(((const bf16*)h_src)[idx]);
#pragma unroll
          for (int h = 0; h < 8; ++h) z[j][h] += ew_s[wv][i * 8 + h] * x;
        }
      }
      asm volatile("s_waitcnt lgkmcnt(0)" ::: "memory");
    }
  }

  // z -> LDS bf16: row = wv*4+j, elems k' = lane*8 + h (one b128 per dst)
#pragma unroll
  for (int j = 0; j < 4; ++j) {
    int4 pk;
    pk.x = ((int)f2bf(z[j][1]) << 16) | f2bf(z[j][0]);
    pk.y = ((int)f2bf(z[j][3]) << 16) | f2bf(z[j][2]);
    pk.z = ((int)f2bf(z[j][5]) << 16) | f2bf(z[j][4]);
    pk.w = ((int)f2bf(z[j][7]) << 16) | f2bf(z[j][6]);
    *(int4*)&Zl[(wv * 4 + j) * 520 + lane * 8] = pk;
  }
  __syncthreads();

  // MFMA epilogue: wave wv computes rows 0..15, cols wv*16..wv*16+15
  int row = lane & 15;
  int kg = lane >> 4;
  f32x4 acc = {0.f, 0.f, 0.f, 0.f};
#pragma unroll
  for (int kt = 0; kt < 16; ++kt) {
    int kbase = kt * 32 + kg * 8;
    short8 a = *(const short8*)&Zl[row * 520 + kbase];
    short8 b = *(const short8*)&Wrt[(size_t)(wv * 16 + row) * 512 + kbase];
    acc = __builtin_amdgcn_mfma_f32_16x16x32_bf16(a, b, acc, 0, 0, 0);
  }

  int col = wv * 16 + row;
  float o_r[4];
#pragma unroll
  for (int r = 0; r < 4; ++r) {
    int dloc = kg * 4 + r;
    int d = d0 + dloc;
    float o = 0.f;
    if (d < Nd) {
      float v = __bfloat162float(h_res[(size_t)d * 64 + col]) + 0.125f * acc[r];
      o = v > 0.f ? v : expm1f(v);
      out_f32[(size_t)d * 64 + col] = o;
    }
    o_r[r] = o;
  }

  if (WRITE_AJ) {
#pragma unroll
    for (int r = 0; r < 4; ++r) {
      int dloc = kg * 4 + r;
#pragma unroll
      for (int h = 0; h < 8; ++h) {
        float p = o_r[r] * vj_next[h * 64 + col];
        p += __shfl_xor(p, 1, 64);
        p += __shfl_xor(p, 2, 64);
        p += __shfl_xor(p, 4, 64);
        p += __shfl_xor(p, 8, 64);
        if (row == 0) ajp[wv][dloc][h] = p;
      }
    }
    __syncthreads();
    if (t < 128) {
      int dloc = t >> 3, h = t & 7;
      int d = d0 + dloc;
      if (d < Nd) {
        float s = ajp[0][dloc][h] + ajp[1][dloc][h] + ajp[2][dloc][h] +
                  ajp[3][dloc][h];
        aj_next[(size_t)d * 8 + h] = s;
      }
    }
  }
}

// ---------------------------------------------------------------------------
extern "C" void kernel_launch(void* const* d_in, const int* in_sizes, int n_in,
                              void* d_out, int out_size, void* d_ws,
                              size_t ws_size, hipStream_t stream) {
  const void* op_nodes = d_in[0];
  const void* mc_nodes = d_in[1];
  const int* ei        = (const int*)d_in[2];
  const void* W_op     = d_in[3];
  const void* b_op     = d_in[4];
  const void* W_mc     = d_in[5];
  const void* b_mc     = d_in[6];
  const void* W_om     = d_in[7];
  const void* att_om   = d_in[8];
  const void* W_mo     = d_in[9];
  const void* att_mo   = d_in[10];

  int n_op = in_sizes[0] / 4;
  int n_mc = in_sizes[1] / 2;
  int E    = in_sizes[2] / 2;

  char* ws = (char*)d_ws;
  size_t off = 0;
  auto alloc = [&](size_t bytes) -> void* {
    void* p = ws + off;
    off = (off + bytes + 255) & ~(size_t)255;
    return p;
  };
  int* flags   = (int*)alloc(16);
  bf16* h_op   = (bf16*)alloc((size_t)n_op * 64 * 2);
  bf16* h_mc   = (bf16*)alloc((size_t)n_mc * 64 * 2);
  float* aj_op = (float*)alloc((size_t)n_op * 8 * 4);
  float* aj_mc = (float*)alloc((size_t)n_mc * 8 * 4);
  float* vj_om = (float*)alloc(512 * 4);
  float* vj_mo = (float*)alloc(512 * 4);
  bf16* Wrt_om = (bf16*)alloc(32768 * 2);
  bf16* Wrt_mo = (bf16*)alloc(32768 * 2);
  float* ew    = (float*)alloc((size_t)E * 8 * 4);   // shared by both layers
  int* cnt1  = (int*)alloc((size_t)n_mc * 4);
  int* cnt2  = (int*)alloc((size_t)n_op * 4);
  int* offs1 = (int*)alloc((size_t)(n_mc + 1) * 4);
  int* cur1  = (int*)alloc((size_t)n_mc * 4);
  int* srcs1 = (int*)alloc((size_t)E * 4);
  int* offs2 = (int*)alloc((size_t)(n_op + 1) * 4);
  int* cur2  = (int*)alloc((size_t)n_op * 4);
  int* srcs2 = (int*)alloc((size_t)E * 4);
  int* bsum1 = (int*)alloc(256 * 4);
  int* bsum2 = (int*)alloc(256 * 4);
  int* bscan1 = (int*)alloc(256 * 4);
  int* bscan2 = (int*)alloc(256 * 4);

  float* out_op = (float*)d_out;
  float* out_mc = out_op + (size_t)n_op * 64;  // layer-1 result + layer-2 src

  hipMemsetAsync(cnt1, 0, (size_t)n_mc * 4, stream);
  hipMemsetAsync(cnt2, 0, (size_t)n_op * 4, stream);

  detect_kernel<<<1, 1024, 0, stream>>>(ei, (const unsigned short*)op_nodes,
                                        flags);

  prep_all<<<256, 256, 0, stream>>>(W_om, att_om, W_mo, att_mo, flags, vj_om,
                                    Wrt_om, vj_mo, Wrt_mo);

  int nbo = (n_op + 3) / 4, nbm = (n_mc + 3) / 4;
  node_all<<<nbo + nbm, 256, 0, stream>>>(op_nodes, W_op, b_op, mc_nodes, W_mc,
                                          b_mc, flags, vj_om, h_op, aj_op, h_mc,
                                          n_op, n_mc, nbo);

  count_edges<<<(E + 255) / 256, 256, 0, stream>>>(ei, E, flags, cnt1, cnt2);

  int nb1 = (n_mc + 2047) / 2048, nb2 = (n_op + 2047) / 2048;
  scan_bsum2<<<nb1 + nb2, 256, 0, stream>>>(cnt1, n_mc, nb1, cnt2, n_op, bsum1,
                                            bsum2);
  scan_btop2<<<1, 128, 0, stream>>>(bsum1, nb1, bscan1, offs1, n_mc, bsum2, nb2,
                                    bscan2, offs2, n_op);
  scan_write2<<<nb1 + nb2, 256, 0, stream>>>(cnt1, n_mc, nb1, bscan1, offs1,
                                             cur1, cnt2, n_op, bscan2, offs2,
                                             cur2);
  fill_edges<<<(E + 255) / 256, 256, 0, stream>>>(ei, E, flags, cur1, srcs1,
                                                  cur2, srcs2);

  // GAT1: op -> mc
  gat_stats<<<(n_mc + 31) / 32, 256, 0, stream>>>(n_mc, offs1, srcs1, aj_op, ew);
  gat_gather<true, false><<<(n_mc + 15) / 16, 256, 0, stream>>>(
      n_mc, offs1, srcs1, ew, h_op, Wrt_om, h_mc, out_mc, vj_mo, aj_mc);
  // GAT2: mc -> op (src = layer-1 mc output, f32 in d_out)
  gat_stats<<<(n_op + 31) / 32, 256, 0, stream>>>(n_op, offs2, srcs2, aj_mc, ew);
  gat_gather<false, true><<<(n_op + 15) / 16, 256, 0, stream>>>(
      n_op, offs2, srcs2, ew, out_mc, Wrt_mo, h_op, out_op,
      (const float*)nullptr, (float*)nullptr);
}